// Round 6
// baseline (523.263 us; speedup 1.0000x reference)
//
#include <hip/hip_runtime.h>
#include <hip/hip_bf16.h>
#include <math.h>

// Problem constants (from reference)
#define T_LEN 256
#define NSYM 64
#define NVAL 32
#define XSTRIDE 68   // 64 + 4 pad: staggers gather-write banks; reads are broadcast

__device__ __forceinline__ float gelu_exact(float x) {
    // jax.nn.gelu(approximate=False) = 0.5*x*(1+erf(x/sqrt(2)))
    return 0.5f * x * (1.0f + erff(x * 0.70710678118654752440f));
}
__device__ __forceinline__ float sigmoid_f(float x) {
    return 1.0f / (1.0f + expf(-x));
}

// ---------------------------------------------------------------------------
// K1 v4: fully fused per-batch kernel.
// Fix vs v3 (~150us, serial per-event HBM latency chains): per 64-event tile,
// ALL 256 threads cooperatively gather the compacted evidence rows into LDS
// (768 in-flight lane loads -> one HBM latency per TILE, not per event),
// then each wave computes its events from LDS broadcasts against the
// register-resident W1 column. Phase B is issue-bound, not latency-bound.
//   A) masks -> compacted event lists in LDS (uchar), packed idx codes
//   B) per type {map,step}: tile-gather X -> LDS; wave computes events
//      i = wv,wv+4,... : 16x ds_read_b128 broadcast + 64 reg FMA + GELU +
//      W2 dot + 6-level shfl reduce + sigmoid + LDS atomicAdd scatter.
//   C) 3-step graph walk in LDS, write graph_state[b][128].
// LDS ~44 KB -> 2 blocks/CU. launch_bounds(256,2) keeps w1c[64] unspilled.
// ---------------------------------------------------------------------------
__global__ __launch_bounds__(256, 2) void k1_fused(
    const float* __restrict__ evidence,
    const int* __restrict__ event_marker,
    const int* __restrict__ source_idx,
    const int* __restrict__ source_valid,
    const int* __restrict__ tsym_idx,
    const int* __restrict__ tsym_valid,
    const int* __restrict__ tval_idx,
    const int* __restrict__ tval_valid,
    const int* __restrict__ query_idx,
    const int* __restrict__ query_valid,
    const float* __restrict__ symbol_emb,   // [64,64]
    const float* __restrict__ value_emb,    // [32,64]
    const float* __restrict__ mg_W1, const float* __restrict__ mg_b1,
    const float* __restrict__ mg_W2, const float* __restrict__ mg_b2,
    const float* __restrict__ sg_W1, const float* __restrict__ sg_b1,
    const float* __restrict__ sg_W2, const float* __restrict__ sg_b2,
    float* __restrict__ state_out)          // [B,128]
{
    __shared__ int   s_code[T_LEN];          // src | ts<<8 | tv<<16
    __shared__ unsigned char l_map[T_LEN], l_step[T_LEN];
    __shared__ int   cnts[2];
    __shared__ float mapM[NSYM * NVAL];      // 8 KB
    __shared__ float stepM[NSYM * NSYM];     // 16 KB
    __shared__ float X[64 * XSTRIDE];        // 17.4 KB staged evidence tile
    __shared__ float wk[64], wk2[64], accv[32], accs[64];

    const int tid  = threadIdx.x;
    const int b    = blockIdx.x;
    const int lane = tid & 63;
    const int wv   = tid >> 6;

    // ---- phase A: masks, lists, zero memories ----
    if (tid < 2) cnts[tid] = 0;
    for (int i = tid; i < NSYM * NVAL;  i += 256) mapM[i]  = 0.f;
    for (int i = tid; i < NSYM * NSYM;  i += 256) stepM[i] = 0.f;
    __syncthreads();

    {
        const int e  = b * T_LEN + tid;
        const int m  = event_marker[e];
        const int sv = source_valid[e];
        int src = source_idx[e]; src = src < 0 ? 0 : (src > 63 ? 63 : src);
        int ts  = tsym_idx[e];   ts  = ts  < 0 ? 0 : (ts  > 63 ? 63 : ts);
        int tv  = tval_idx[e];   tv  = tv  < 0 ? 0 : (tv  > 31 ? 31 : tv);
        s_code[tid] = src | (ts << 8) | (tv << 16);
        const bool mm = ((m == 1) || (m == 2)) && (sv != 0) && (tval_valid[e] != 0);
        const bool sm = (m == 3) && (sv != 0) && (tsym_valid[e] != 0);
        if (mm) { int i = atomicAdd(&cnts[0], 1); l_map[i]  = (unsigned char)tid; }
        if (sm) { int i = atomicAdd(&cnts[1], 1); l_step[i] = (unsigned char)tid; }
    }
    __syncthreads();

    // ---- phase B: tile-gathered gate MLPs, weights in registers ----
    #pragma unroll 1
    for (int type = 0; type < 2; ++type) {
        const int cnt = cnts[type];              // uniform across block
        if (cnt == 0) continue;
        const float* __restrict__ W1g = (type == 0) ? mg_W1 : sg_W1;
        const float* __restrict__ W2g = (type == 0) ? mg_W2 : sg_W2;
        const float* __restrict__ b1g = (type == 0) ? mg_b1 : sg_b1;
        const float* __restrict__ b2g = (type == 0) ? mg_b2 : sg_b2;
        const unsigned char* list = (type == 0) ? l_map : l_step;

        // lane j's W1 column (64 VGPRs) — coalesced, L2-hot after first blocks
        float w1c[64];
        #pragma unroll
        for (int k = 0; k < 64; ++k) w1c[k] = W1g[k * 64 + lane];
        const float b1j = b1g[lane];
        const float w2j = W2g[lane];
        const float b2v = b2g[0];

        #pragma unroll 1
        for (int tb = 0; tb < cnt; tb += 64) {
            __syncthreads();                     // X free from previous use
            // cooperative gather: 4 threads per row, 16 floats each,
            // 768 lane-loads in flight -> one HBM latency per tile
            {
                const int r = tid >> 2, f4 = tid & 3;
                const int slot = tb + r;
                if (slot < cnt) {
                    const int tev = list[slot];
                    const float4* __restrict__ xg =
                        (const float4*)(evidence + ((size_t)b * T_LEN + tev) * 64)
                        + f4 * 4;
                    float4* xd = (float4*)&X[r * XSTRIDE + f4 * 16];
                    const float4 v0 = xg[0], v1 = xg[1], v2 = xg[2], v3 = xg[3];
                    xd[0] = v0; xd[1] = v1; xd[2] = v2; xd[3] = v3;
                }
            }
            __syncthreads();

            const int tcnt = (cnt - tb) < 64 ? (cnt - tb) : 64;
            #pragma unroll 1
            for (int i = wv; i < tcnt; i += 4) {
                const float4* __restrict__ xrow = (const float4*)&X[i * XSTRIDE];
                float h0 = b1j, h1 = 0.f, h2 = 0.f, h3 = 0.f;
                #pragma unroll
                for (int kq = 0; kq < 16; ++kq) {
                    const float4 xv = xrow[kq];  // uniform addr -> broadcast
                    h0 = fmaf(xv.x, w1c[4 * kq + 0], h0);
                    h1 = fmaf(xv.y, w1c[4 * kq + 1], h1);
                    h2 = fmaf(xv.z, w1c[4 * kq + 2], h2);
                    h3 = fmaf(xv.w, w1c[4 * kq + 3], h3);
                }
                const float hj = (h0 + h1) + (h2 + h3);
                float gj = gelu_exact(hj) * w2j;
                gj += __shfl_xor(gj, 1);  gj += __shfl_xor(gj, 2);
                gj += __shfl_xor(gj, 4);  gj += __shfl_xor(gj, 8);
                gj += __shfl_xor(gj, 16); gj += __shfl_xor(gj, 32);

                if (lane == 0) {
                    const float g = sigmoid_f(gj + b2v);
                    const int code = s_code[list[tb + i]];
                    if (type == 0)
                        atomicAdd(&mapM[(code & 63) * NVAL + ((code >> 16) & 31)], g);
                    else
                        atomicAdd(&stepM[(code & 63) * NSYM + ((code >> 8) & 63)], g);
                }
            }
        }
    }
    __syncthreads();

    // ---- phase C: 3-step graph walk (memories live in LDS) ----
    {
        int q = query_idx[b]; q = q < 0 ? 0 : (q > 63 ? 63 : q);
        const float qv = (query_valid[b] != 0) ? 1.0f : 0.0f;
        if (tid < 64) wk[tid]  = (tid == q) ? qv : 0.f;
        if (tid < 32) accv[tid] = qv * mapM[q * NVAL + tid];
        if (tid < 64) accs[tid] = qv * symbol_emb[q * 64 + tid];
        __syncthreads();

        for (int st = 0; st < 3; ++st) {
            if (tid < 64) {
                float s = 0.f;
                #pragma unroll 8
                for (int s0 = 0; s0 < 64; ++s0) s += wk[s0] * stepM[s0 * NSYM + tid];
                wk2[tid] = s;
            }
            __syncthreads();
            if (tid < 64) wk[tid] = wk2[tid];
            __syncthreads();
            if (tid < 32) {
                float s = 0.f;
                #pragma unroll 8
                for (int s0 = 0; s0 < 64; ++s0) s += wk[s0] * mapM[s0 * NVAL + tid];
                accv[tid] += s;
            }
            if (tid < 64) {
                float s = 0.f;
                #pragma unroll 8
                for (int s0 = 0; s0 < 64; ++s0) s += wk[s0] * symbol_emb[s0 * 64 + tid];
                accs[tid] += s;
            }
            __syncthreads();
        }

        if (tid < 64) {
            float s = 0.f;
            #pragma unroll 8
            for (int v = 0; v < 32; ++v) s += accv[v] * value_emb[v * 64 + tid];
            state_out[(size_t)b * 128 + tid]      = accs[tid];
            state_out[(size_t)b * 128 + 64 + tid] = s;
        }
    }
}

// ---------------------------------------------------------------------------
// K2: output heads (unchanged — isolating the k1 change).
// out layout: logits [B*32] then feedback [B*64] (tuple concat).
// ---------------------------------------------------------------------------
__global__ __launch_bounds__(256) void k2_heads(
    const float* __restrict__ state,        // [B,128]
    const float* __restrict__ sf_W1, const float* __restrict__ sf_b1,
    const float* __restrict__ sf_W2, const float* __restrict__ sf_b2,
    const float* __restrict__ oh_W1, const float* __restrict__ oh_b1,
    const float* __restrict__ oh_W2, const float* __restrict__ oh_b2,
    float* __restrict__ out, int B)
{
    __shared__ float h_oh[4][64];
    __shared__ float h_sf[4][64];
    const int tid = threadIdx.x;
    const int w = tid >> 6, j = tid & 63;
    const int b = blockIdx.x * 4 + w;
    {
        const float* st = state + (size_t)b * 128;
        float a_oh = oh_b1[j], a_sf = sf_b1[j];
        #pragma unroll 8
        for (int k = 0; k < 128; ++k) {
            const float sv = st[k];
            a_oh += sv * oh_W1[k * 64 + j];
            a_sf += sv * sf_W1[k * 64 + j];
        }
        h_oh[w][j] = gelu_exact(a_oh);
        h_sf[w][j] = gelu_exact(a_sf);
    }
    __syncthreads();

    for (int o = tid; o < 4 * 96; o += 256) {
        const int bb = o / 96, oo = o % 96;
        const int gb = blockIdx.x * 4 + bb;
        if (oo < 32) {
            float s = oh_b2[oo];
            #pragma unroll 8
            for (int jj = 0; jj < 64; ++jj) s += h_oh[bb][jj] * oh_W2[jj * 32 + oo];
            out[(size_t)gb * 32 + oo] = s;
        } else {
            const int dd = oo - 32;
            float s = sf_b2[dd];
            #pragma unroll 8
            for (int jj = 0; jj < 64; ++jj) s += h_sf[bb][jj] * sf_W2[jj * 64 + dd];
            out[(size_t)B * 32 + (size_t)gb * 64 + dd] = s;
        }
    }
}

extern "C" void kernel_launch(void* const* d_in, const int* in_sizes, int n_in,
                              void* d_out, int out_size, void* d_ws, size_t ws_size,
                              hipStream_t stream) {
    const float* evidence      = (const float*)d_in[0];
    const int*   event_marker  = (const int*)d_in[1];
    const int*   source_idx    = (const int*)d_in[2];
    const int*   source_valid  = (const int*)d_in[3];
    const int*   tsym_idx      = (const int*)d_in[4];
    const int*   tsym_valid    = (const int*)d_in[5];
    const int*   tval_idx      = (const int*)d_in[6];
    const int*   tval_valid    = (const int*)d_in[7];
    const int*   query_idx     = (const int*)d_in[8];
    const int*   query_valid   = (const int*)d_in[9];
    const float* symbol_emb    = (const float*)d_in[10];
    const float* value_emb     = (const float*)d_in[11];
    const float* mg_W1 = (const float*)d_in[12]; const float* mg_b1 = (const float*)d_in[13];
    const float* mg_W2 = (const float*)d_in[14]; const float* mg_b2 = (const float*)d_in[15];
    const float* sg_W1 = (const float*)d_in[16]; const float* sg_b1 = (const float*)d_in[17];
    const float* sg_W2 = (const float*)d_in[18]; const float* sg_b2 = (const float*)d_in[19];
    const float* sf_W1 = (const float*)d_in[20]; const float* sf_b1 = (const float*)d_in[21];
    const float* sf_W2 = (const float*)d_in[22]; const float* sf_b2 = (const float*)d_in[23];
    const float* oh_W1 = (const float*)d_in[24]; const float* oh_b1 = (const float*)d_in[25];
    const float* oh_W2 = (const float*)d_in[26]; const float* oh_b2 = (const float*)d_in[27];

    const int B = in_sizes[8];          // 4096
    float* state = (float*)d_ws;        // [B,128] scratch

    k1_fused<<<B, 256, 0, stream>>>(
        evidence, event_marker, source_idx, source_valid,
        tsym_idx, tsym_valid, tval_idx, tval_valid,
        query_idx, query_valid, symbol_emb, value_emb,
        mg_W1, mg_b1, mg_W2, mg_b2, sg_W1, sg_b1, sg_W2, sg_b2,
        state);

    k2_heads<<<B / 4, 256, 0, stream>>>(
        state, sf_W1, sf_b1, sf_W2, sf_b2,
        oh_W1, oh_b1, oh_W2, oh_b2,
        (float*)d_out, B);
}